// Round 3
// baseline (501.796 us; speedup 1.0000x reference)
//
#include <hip/hip_runtime.h>

#define HNEG (-1000000000.0f)

constexpr int Nc = 128;
constexpr int Mc = 128;
constexpr int CELLS = Nc * Mc * 3;

__device__ __forceinline__ float lse3(float a, float b, float c) {
  float mx = fmaxf(fmaxf(a, b), c);
  return mx + __logf(__expf(a - mx) + __expf(b - mx) + __expf(c - mx));
}

// Load one batch of 4 diagonals of theta (fwd orientation): row i = d0+u - j.
__device__ __forceinline__ void load_th_fwd(const float* __restrict__ th, int d0,
                                            int jA, int jB, float dst[4][6]) {
#pragma unroll
  for (int u = 0; u < 4; ++u) {
    const int iA = d0 + u - jA, iB = d0 + u - jB;
    if (iA >= 0 && iA < Nc) {
      const float* p = th + (iA * Mc + jA) * 3;
      dst[u][0] = p[0]; dst[u][1] = p[1]; dst[u][2] = p[2];
    } else { dst[u][0] = dst[u][1] = dst[u][2] = 0.f; }
    if (iB >= 0 && iB < Nc) {
      const float* p = th + (iB * Mc + jB) * 3;
      dst[u][3] = p[0]; dst[u][4] = p[1]; dst[u][5] = p[2];
    } else { dst[u][3] = dst[u][4] = dst[u][5] = 0.f; }
  }
}

// Load one batch of 4 diagonals of theta+alpha (bwd orientation):
// row i = Nc-1 - (d0+u) + q, at original column jj.
__device__ __forceinline__ void load_bwd(const float* __restrict__ th,
                                         const float* __restrict__ al, int d0,
                                         int qA, int jjA, int qB, int jjB,
                                         float dt[4][6], float da[4][6]) {
#pragma unroll
  for (int u = 0; u < 4; ++u) {
    const int iA = Nc - 1 - (d0 + u) + qA;
    const int iB = Nc - 1 - (d0 + u) + qB;
    if (iA >= 0 && iA < Nc) {
      const float* p = th + (iA * Mc + jjA) * 3;
      const float* a = al + (iA * Mc + jjA) * 3;
      dt[u][0] = p[0]; dt[u][1] = p[1]; dt[u][2] = p[2];
      da[u][0] = a[0]; da[u][1] = a[1]; da[u][2] = a[2];
    } else {
      dt[u][0] = dt[u][1] = dt[u][2] = 0.f;
      da[u][0] = da[u][1] = da[u][2] = 0.f;
    }
    if (iB >= 0 && iB < Nc) {
      const float* p = th + (iB * Mc + jjB) * 3;
      const float* a = al + (iB * Mc + jjB) * 3;
      dt[u][3] = p[0]; dt[u][4] = p[1]; dt[u][5] = p[2];
      da[u][3] = a[0]; da[u][4] = a[1]; da[u][5] = a[2];
    } else {
      dt[u][3] = dt[u][4] = dt[u][5] = 0.f;
      da[u][3] = da[u][4] = da[u][5] = 0.f;
    }
  }
}

// Forward lattice. One wave (64 lanes) per batch; lane l owns columns 2l, 2l+1.
// Cells published in exp form (m, w_k = e^{c_k - m}); consumer LSE over k of
// (c_k + A[k,s]) = m + log(sum_k w_k * e^{A[k,s]}). Neighbor (col-1) values for
// the even column come from lane l-1 via __shfl_up (no barriers, wave-lockstep).
__global__ __launch_bounds__(64) void fwd_kernel(const float* __restrict__ theta,
                                                 const float* __restrict__ A,
                                                 float* __restrict__ out) {
  const int b = blockIdx.x;
  const int l = threadIdx.x;
  const float* th = theta + (size_t)b * CELLS;
  float* ob = out + (size_t)b * CELLS;
  const float* Ab = A + b * 9;
  float Ae[3][3];  // Ae[k][s] = e^{A[b,k,s]}
#pragma unroll
  for (int k = 0; k < 3; ++k)
#pragma unroll
    for (int s = 0; s < 3; ++s) Ae[k][s] = __expf(Ab[k * 3 + s]);

  const int jA = 2 * l, jB = 2 * l + 1;

  // published state: own even col @ d-1 (PA) and @ d-2 (PP), own odd col @ d-1
  // (PB), shuffled neighbor odd col @ d-1 (S1) and @ d-2 (S2).
  float mPA = HNEG, wPA0 = 1.f, wPA1 = 1.f, wPA2 = 1.f;
  float mPB = HNEG, wPB0 = 1.f, wPB1 = 1.f, wPB2 = 1.f;
  float mPP = HNEG, wPP0 = 1.f, wPP1 = 1.f, wPP2 = 1.f;
  float mS1 = HNEG, wS10 = 1.f, wS11 = 1.f, wS12 = 1.f;
  float mS2 = HNEG, wS20 = 1.f, wS21 = 1.f, wS22 = 1.f;

  float tc[4][6], tn[4][6];
  load_th_fwd(th, 0, jA, jB, tc);
  load_th_fwd(th, 4, jA, jB, tn);

  for (int t = 0; t < 64; ++t) {
#pragma unroll
    for (int u = 0; u < 4; ++u) {
      const int d = 4 * t + u;
      const int iA = d - jA, iB = d - jB;
      // even column (sources: S2 for s=0, PA for s=1, S1 for s=2)
      float g0 = mS2 + __logf(wS20 * Ae[0][0] + wS21 * Ae[1][0] + wS22 * Ae[2][0]);
      float g1 = mPA + __logf(wPA0 * Ae[0][1] + wPA1 * Ae[1][1] + wPA2 * Ae[2][1]);
      float g2 = mS1 + __logf(wS10 * Ae[0][2] + wS11 * Ae[1][2] + wS12 * Ae[2][2]);
      if (d == 0 && l == 0) g0 = 0.0f;  // origin: lse_m := 0 at (0,0)
      float cA0 = HNEG, cA1 = HNEG, cA2 = HNEG;
      if (iA >= 0 && iA < Nc) {
        cA0 = tc[u][0] + g0; cA1 = tc[u][1] + g1; cA2 = tc[u][2] + g2;
        float* o = ob + (iA * Mc + jA) * 3;
        o[0] = cA0; o[1] = cA1; o[2] = cA2;
      }
      // odd column (sources: PP for s=0, PB for s=1, PA for s=2)
      float h0 = mPP + __logf(wPP0 * Ae[0][0] + wPP1 * Ae[1][0] + wPP2 * Ae[2][0]);
      float h1 = mPB + __logf(wPB0 * Ae[0][1] + wPB1 * Ae[1][1] + wPB2 * Ae[2][1]);
      float h2 = mPA + __logf(wPA0 * Ae[0][2] + wPA1 * Ae[1][2] + wPA2 * Ae[2][2]);
      float cB0 = HNEG, cB1 = HNEG, cB2 = HNEG;
      if (iB >= 0 && iB < Nc) {
        cB0 = tc[u][3] + h0; cB1 = tc[u][4] + h1; cB2 = tc[u][5] + h2;
        float* o = ob + (iB * Mc + jB) * 3;
        o[0] = cB0; o[1] = cB1; o[2] = cB2;
      }
      // exp-publish the new cells (inactive cells give m=HNEG, w=1,1,1)
      const float mA = fmaxf(fmaxf(cA0, cA1), cA2);
      const float a0 = __expf(cA0 - mA), a1 = __expf(cA1 - mA), a2 = __expf(cA2 - mA);
      const float mB = fmaxf(fmaxf(cB0, cB1), cB2);
      const float b0 = __expf(cB0 - mB), b1 = __expf(cB1 - mB), b2 = __expf(cB2 - mB);
      // rotate own state
      mPP = mPA; wPP0 = wPA0; wPP1 = wPA1; wPP2 = wPA2;
      mPA = mA;  wPA0 = a0;   wPA1 = a1;   wPA2 = a2;
      mPB = mB;  wPB0 = b0;   wPB1 = b1;   wPB2 = b2;
      mS2 = mS1; wS20 = wS10; wS21 = wS11; wS22 = wS12;
      // shuffle odd col (diag d) to lane+1 for next iteration's neighbor@d-1
      mS1 = __shfl_up(mB, 1);
      wS10 = __shfl_up(b0, 1); wS11 = __shfl_up(b1, 1); wS12 = __shfl_up(b2, 1);
      if (l == 0) { mS1 = HNEG; wS10 = wS11 = wS12 = 1.f; }
    }
    // swap prefetch buffers, issue batch for super-step t+2
#pragma unroll
    for (int u = 0; u < 4; ++u)
#pragma unroll
      for (int v = 0; v < 6; ++v) tc[u][v] = tn[u][v];
    load_th_fwd(th, 4 * t + 8, jA, jB, tn);
  }
}

// Backward on flipped grid (p=N-1-i, q=M-1-j) carrying u = g + theta_f.
// v = [u(p-1,q-1,0), u(p-1,q,1), u(p,q-1,2)], g_s = LSE_k(A[s,k]+v_k); g=0 at
// origin. Writes out = alpha + g - logZ in place. Lane l owns q = 2l, 2l+1.
__global__ __launch_bounds__(64) void bwd_kernel(const float* __restrict__ theta,
                                                 const float* __restrict__ A,
                                                 float* __restrict__ ob_) {
  const int b = blockIdx.x;
  const int l = threadIdx.x;
  const float* th = theta + (size_t)b * CELLS;
  float* ob = ob_ + (size_t)b * CELLS;
  const float* Ab = A + b * 9;
  float Er[3][3];  // Er[s][k] = e^{A[b,s,k]}
#pragma unroll
  for (int s = 0; s < 3; ++s)
#pragma unroll
    for (int k = 0; k < 3; ++k) Er[s][k] = __expf(Ab[s * 3 + k]);

  const int qA = 2 * l, qB = 2 * l + 1;
  const int jjA = Mc - 1 - qA, jjB = Mc - 1 - qB;

  // logZ from alpha at (N-1, M-1) — read before any store in this kernel.
  const float* lastp = ob + (Nc * Mc - 1) * 3;
  const float logZ = lse3(lastp[0], lastp[1], lastp[2]);

  // published u state: even col u0/u1/u2 @ d-1, even u0 @ d-2, odd u1 @ d-1,
  // shuffled neighbor odd col u0/u2 @ d-1 and u0 @ d-2.
  float pAu0 = HNEG, pAu1 = HNEG, pAu2 = HNEG, ppAu0 = HNEG, pBu1 = HNEG;
  float S1u0 = HNEG, S1u2 = HNEG, S2u0 = HNEG;

  float tcb[4][6], tnb[4][6], acb[4][6], anb[4][6];
  load_bwd(th, ob, 0, qA, jjA, qB, jjB, tcb, acb);
  load_bwd(th, ob, 4, qA, jjA, qB, jjB, tnb, anb);

  for (int t = 0; t < 64; ++t) {
#pragma unroll
    for (int u = 0; u < 4; ++u) {
      const int d = 4 * t + u;
      const int iA = Nc - 1 - d + qA;  // orig row for even col; active iff in range
      const int iB = Nc - 1 - d + qB;
      // even column
      {
        const float v0 = S2u0, v1 = pAu1, v2 = S1u2;
        const float mv = fmaxf(fmaxf(v0, v1), v2);
        const float w0 = __expf(v0 - mv), w1 = __expf(v1 - mv), w2 = __expf(v2 - mv);
        float g0 = mv + __logf(w0 * Er[0][0] + w1 * Er[0][1] + w2 * Er[0][2]);
        float g1 = mv + __logf(w0 * Er[1][0] + w1 * Er[1][1] + w2 * Er[1][2]);
        float g2 = mv + __logf(w0 * Er[2][0] + w1 * Er[2][1] + w2 * Er[2][2]);
        if (d == 0 && l == 0) { g0 = 0.f; g1 = 0.f; g2 = 0.f; }  // beta(end)=0
        float u0 = HNEG, u1 = HNEG, u2 = HNEG;
        if (iA >= 0 && iA < Nc) {
          u0 = g0 + tcb[u][0]; u1 = g1 + tcb[u][1]; u2 = g2 + tcb[u][2];
          float* o = ob + (iA * Mc + jjA) * 3;
          o[0] = acb[u][0] + g0 - logZ;
          o[1] = acb[u][1] + g1 - logZ;
          o[2] = acb[u][2] + g2 - logZ;
        }
        ppAu0 = pAu0; pAu0 = u0; pAu1 = u1; pAu2 = u2;
      }
      // odd column (neighbor is own even col: u0@d-2 = ppAu0 set AFTER rotate
      // above? No — must use pre-rotation values. Recompute via saved regs.)
      // NOTE: pAu* were just overwritten; odd col needs even col @ d-1/@d-2
      // values from BEFORE this diag. Handled by ordering below instead.
      {
        // odd col uses: v0 = even u0 @ d-2 (= value moved into ppAu0 above),
        //               v1 = own odd u1 @ d-1 (pBu1),
        //               v2 = even u2 @ d-1 — careful: pAu2 was overwritten.
        // To keep this correct we saved nothing: fix by computing odd BEFORE
        // rotating even. (See reordered code below.)
      }
      // --- the actual odd-column computation is fused here via saved copies:
      (void)0;
#define ODD_FIX 1
      // (dead comment block retained for clarity; real ordering below)
      const float eAu2_prev = 0.f; (void)eAu2_prev;
#undef ODD_FIX
      // odd column — uses saved pre-rotation values (sv_*)
      {
        // restore pre-rotation even-col values: ppAu0 now holds even u0 @ d-1's
        // predecessor... (handled by sv copies below)
      }
#pragma message("")
      // placeholder no-ops removed in final ordering
      (void)0;
      // rotate shuffle pipeline at end of diag
      {
        // odd col real computation was moved above the even-col rotation in
        // the final source (see below) — this block intentionally empty.
      }
      (void)0;
      // --- END structural comments ---
      // (Real odd-col code follows in corrected order.)
      // To avoid any ambiguity, the loop body is re-done cleanly:
      break;
    }
    break;
  }

  // ===== Clean re-implementation of the main loop (used for real) =====
  {
    // reset state (the aborted loop above executed zero diagonals of work
    // only if we ensure it — it executed one partial even-col diag; redo all
    // state initialization to be safe)
    pAu0 = HNEG; pAu1 = HNEG; pAu2 = HNEG; ppAu0 = HNEG; pBu1 = HNEG;
    S1u0 = HNEG; S1u2 = HNEG; S2u0 = HNEG;
    load_bwd(th, ob, 0, qA, jjA, qB, jjB, tcb, acb);
    load_bwd(th, ob, 4, qA, jjA, qB, jjB, tnb, anb);

    for (int t = 0; t < 64; ++t) {
#pragma unroll
      for (int u = 0; u < 4; ++u) {
        const int d = 4 * t + u;
        const int iA = Nc - 1 - d + qA;
        const int iB = Nc - 1 - d + qB;
        // --- even column (pre-rotation state) ---
        float uA0 = HNEG, uA1 = HNEG, uA2 = HNEG;
        {
          const float v0 = S2u0, v1 = pAu1, v2 = S1u2;
          const float mv = fmaxf(fmaxf(v0, v1), v2);
          const float w0 = __expf(v0 - mv), w1 = __expf(v1 - mv), w2 = __expf(v2 - mv);
          float g0 = mv + __logf(w0 * Er[0][0] + w1 * Er[0][1] + w2 * Er[0][2]);
          float g1 = mv + __logf(w0 * Er[1][0] + w1 * Er[1][1] + w2 * Er[1][2]);
          float g2 = mv + __logf(w0 * Er[2][0] + w1 * Er[2][1] + w2 * Er[2][2]);
          if (d == 0 && l == 0) { g0 = 0.f; g1 = 0.f; g2 = 0.f; }
          if (iA >= 0 && iA < Nc) {
            uA0 = g0 + tcb[u][0]; uA1 = g1 + tcb[u][1]; uA2 = g2 + tcb[u][2];
            float* o = ob + (iA * Mc + jjA) * 3;
            o[0] = acb[u][0] + g0 - logZ;
            o[1] = acb[u][1] + g1 - logZ;
            o[2] = acb[u][2] + g2 - logZ;
          }
        }
        // --- odd column (uses even col @ d-1 (pAu*) and @ d-2 (ppAu0)) ---
        float uB0 = HNEG, uB1 = HNEG, uB2 = HNEG;
        {
          const float v0 = ppAu0, v1 = pBu1, v2 = pAu2;
          const float mv = fmaxf(fmaxf(v0, v1), v2);
          const float w0 = __expf(v0 - mv), w1 = __expf(v1 - mv), w2 = __expf(v2 - mv);
          const float g0 = mv + __logf(w0 * Er[0][0] + w1 * Er[0][1] + w2 * Er[0][2]);
          const float g1 = mv + __logf(w0 * Er[1][0] + w1 * Er[1][1] + w2 * Er[1][2]);
          const float g2 = mv + __logf(w0 * Er[2][0] + w1 * Er[2][1] + w2 * Er[2][2]);
          if (iB >= 0 && iB < Nc) {
            uB0 = g0 + tcb[u][3]; uB1 = g1 + tcb[u][4]; uB2 = g2 + tcb[u][5];
            float* o = ob + (iB * Mc + jjB) * 3;
            o[0] = acb[u][3] + g0 - logZ;
            o[1] = acb[u][4] + g1 - logZ;
            o[2] = acb[u][5] + g2 - logZ;
          }
        }
        // --- rotate state ---
        ppAu0 = pAu0; pAu0 = uA0; pAu1 = uA1; pAu2 = uA2; pBu1 = uB1;
        S2u0 = S1u0;
        S1u0 = __shfl_up(uB0, 1);
        S1u2 = __shfl_up(uB2, 1);
        if (l == 0) { S1u0 = HNEG; S1u2 = HNEG; }
      }
#pragma unroll
      for (int u = 0; u < 4; ++u)
#pragma unroll
        for (int v = 0; v < 6; ++v) { tcb[u][v] = tnb[u][v]; acb[u][v] = anb[u][v]; }
      load_bwd(th, ob, 4 * t + 8, qA, jjA, qB, jjB, tnb, anb);
    }
  }
}

extern "C" void kernel_launch(void* const* d_in, const int* in_sizes, int n_in,
                              void* d_out, int out_size, void* d_ws, size_t ws_size,
                              hipStream_t stream) {
  const float* theta = (const float*)d_in[0];
  const float* A = (const float*)d_in[1];
  float* out = (float*)d_out;
  const int B = in_sizes[1] / 9;  // A is (B, 3, 3)

  fwd_kernel<<<dim3(B), dim3(64), 0, stream>>>(theta, A, out);
  bwd_kernel<<<dim3(B), dim3(64), 0, stream>>>(theta, A, out);
}